// Round 14
// baseline (1777.886 us; speedup 1.0000x reference)
//
#include <hip/hip_runtime.h>
#include <stdint.h>

typedef unsigned short u16;
typedef uint32_t u32;
typedef __attribute__((ext_vector_type(4))) u32 u32x4;
typedef __attribute__((ext_vector_type(8))) short v8s;
typedef __attribute__((ext_vector_type(4))) float f32x4;

// ---------------- workspace layout (bytes) ----------------
// h  : u32 [2 buf][4 grp][16 row][512 hid]   @ 0        (262144 B)
//      word = (bf16_hi<<16)|(bf16_lo&0xFFFE)|tag, tag=(t>>1)&1
// wf : u16 [32 wg][4 nt][24 c][64 lane][16]  @ 262144   (6291456 B)
//      n-tile nt: h=nt>>1 (unit-half), t2=nt&1 (0: i|f, 1: g|o)
#define OFF_H  0
#define OFF_WF 262144

__device__ __forceinline__ u16 bf_hi(float v) {
  return (u16)(__builtin_bit_cast(u32, v) >> 16);
}
__device__ __forceinline__ float bf_up(u16 h) {
  return __builtin_bit_cast(float, (u32)h << 16);
}
__device__ __forceinline__ float tanhf_fast(float x) {
  float e = __expf(2.f * x);
  return 1.f - 2.f / (e + 1.f);
}
__device__ __forceinline__ float sigm(float x) {
  return 1.f / (1.f + __expf(-x));
}
// v_perm_b32 packers: pkhi(a,b) = (b&0xffff0000)|(a>>16); pklo = (b<<16)|(a&0xffff)
__device__ __forceinline__ u32 pkhi(u32 a, u32 b) { return __builtin_amdgcn_perm(b, a, 0x07060302u); }
__device__ __forceinline__ u32 pklo(u32 a, u32 b) { return __builtin_amdgcn_perm(b, a, 0x05040100u); }

// ---------------- init: buf0 = 0 (h0 valid, tag 0), buf1 = 1 (invalid at t=1)
__global__ void k_init(u32* h) {
  int i = blockIdx.x * 256 + threadIdx.x;   // 65536 words
  if (i < 65536) h[i] = (i < 32768) ? 0u : 1u;
}

// ---------------- pre-pack W_ih / W_hh into MFMA fragment order, bf16 hi/lo --
// WG wg owns units [wg*16, wg*16+16). n-tile nt: unit-half h=nt>>1, pair t2=nt&1.
// col n16 = lane&15: q = t2*2 + (n16>>3), u = h*8 + (n16&7), R = q*512 + wg*16 + u.
// chunk c: 0..7 -> W_ih (k=c*32+8*(lane>>4)+i), 8..23 -> W_hh analog.
__global__ void k_prep(const float* __restrict__ Wih, const float* __restrict__ Whh,
                       u16* __restrict__ wf) {
  int idx = blockIdx.x * 256 + threadIdx.x;   // 32*4*24*64 = 196608
  if (idx >= 196608) return;
  int lane = idx & 63;
  int c  = (idx >> 6) % 24;
  int r2 = (idx >> 6) / 24;        // wg*4 + nt
  int nt = r2 & 3;
  int wg = r2 >> 2;
  int n16 = lane & 15;
  int h = nt >> 1, t2 = nt & 1;
  int q = t2 * 2 + (n16 >> 3);
  int u = h * 8 + (n16 & 7);
  int R = q * 512 + wg * 16 + u;
  int gq = lane >> 4;
  const float* src = (c < 8) ? (Wih + (size_t)R * 256 + c * 32 + 8 * gq)
                             : (Whh + (size_t)R * 512 + (c - 8) * 32 + 8 * gq);
  u16* d = wf + (size_t)idx * 16;
#pragma unroll
  for (int i = 0; i < 8; ++i) {
    float v = src[i];
    u16 hi = bf_hi(v);
    float lo = v - bf_up(hi);
    d[i] = hi;
    d[8 + i] = bf_hi(lo);
  }
}

// ---------------- asm helpers ----------------
#define LOADP(DST, PTR) \
  asm volatile("global_load_dwordx4 %0, %1, off" : "=v"(DST) : "v"(PTR))
#define LOADC(DST, PTR) \
  asm volatile("global_load_dwordx4 %0, %1, off sc0 sc1" : "=v"(DST) : "v"(PTR))
#define STORED(PTR, VAL) \
  asm volatile("global_store_dword %0, %1, off sc0 sc1" :: "v"(PTR), "v"(VAL) : "memory")

#define WAITV_(N) { asm volatile("s_waitcnt vmcnt(" #N ")" ::: "memory"); \
                    __builtin_amdgcn_sched_barrier(0); }
#define WAITV(N) WAITV_(N)

#define MFMA16(a, b, c) __builtin_amdgcn_mfma_f32_16x16x32_bf16((a), (b), (c), 0, 0, 0)
#define BC(x) __builtin_bit_cast(v8s, x)

// 3 MFMAs of one (k-chunk, n-tile): h_hi*(w_hi+w_lo) + h_lo*w_hi
#define MM3(AH, AL, BHI, BLO, ACC) { \
  v8s bh_ = BC(BHI), bl_ = BC(BLO); \
  (ACC) = MFMA16((AH), bh_, (ACC)); \
  (ACC) = MFMA16((AH), bl_, (ACC)); \
  (ACC) = MFMA16((AL), bh_, (ACC)); }

// tag check of chunk j: all 8 LSBs == texp (wave-uniform verdict)
#define TAGOK(j) (__all((( (HA[2*(j)][0]^texp) | (HA[2*(j)][1]^texp) \
                         | (HA[2*(j)][2]^texp) | (HA[2*(j)][3]^texp) \
                         | (HA[2*(j)+1][0]^texp) | (HA[2*(j)+1][1]^texp) \
                         | (HA[2*(j)+1][2]^texp) | (HA[2*(j)+1][3]^texp)) & 1u) == 0u))

// consume chunk j: perm-unpack hi/lo + 4 n-tiles x 3 MFMAs with BH[j]
#define CONSJ(j) { \
  u32x4 w0 = HA[2*(j)], w1 = HA[2*(j)+1]; \
  u32x4 hiw, low; \
  hiw[0] = pkhi(w0[0], w0[1]); hiw[1] = pkhi(w0[2], w0[3]); \
  hiw[2] = pkhi(w1[0], w1[1]); hiw[3] = pkhi(w1[2], w1[3]); \
  low[0] = pklo(w0[0], w0[1]); low[1] = pklo(w0[2], w0[3]); \
  low[2] = pklo(w1[0], w1[1]); low[3] = pklo(w1[2], w1[3]); \
  v8s ah = BC(hiw), al = BC(low); \
  MM3(ah, al, BH[j][0], BH[j][1], acc[0]); \
  MM3(ah, al, BH[j][2], BH[j][3], acc[1]); \
  MM3(ah, al, BH[j][4], BH[j][5], acc[2]); \
  MM3(ah, al, BH[j][6], BH[j][7], acc[3]); }

#define ISSUEJ(j) { LOADC(HA[2*(j)], pp[j]); LOADC(HA[2*(j)+1], pp[j] + 4); }
#define RISS(c)  if (pend & (1u<<(c))) ISSUEJ(c)
#define RCON(c)  if (pend & (1u<<(c))) { if (TAGOK(c)) { CONSJ(c); pend &= ~(1u<<(c)); } }

// ---------------- persistent recurrence kernel ----------------
// Grid 128 = 4 batch-groups x 32 WGs, 256 thr (4 waves). Group g owns rows
// [g*16,g*16+16); WG wg owns 16 hidden units (4 n-tiles: {i|f, g|o} x 2
// unit-halves). Waves split K 4-ways; one barrier/step (red double-buffered).
// NARROW RING (r14): 32 producers/consumers per ring (was 64) -> tighter
// max-arrival jitter + half the MALL poll contention. Wave-pair duplicate
// reduce keeps the r11 gate/shuffle path and the exact r11 vmcnt ledger:
// loop-top queue [EA4, ST4]; phase-1 waits vmcnt(4); after +tok+H8 chunk j
// ready at vmcnt(6-2j) [ST4+tok retired before c0]; tok at vmcnt(0).
__global__ __launch_bounds__(256, 1) void k_lstm(
    const int* __restrict__ xin, const float* __restrict__ emb,
    const float* __restrict__ bih, const float* __restrict__ bhh,
    uint8_t* __restrict__ ws, float* __restrict__ dout)
{
  const int bid = blockIdx.x;
  const int wg = bid & 31;
  const int g  = bid >> 5;
  const int tid = threadIdx.x;
  const int wv = tid >> 6;
  const int lane = tid & 63;
  const int cl = lane & 15;
  const int gq = lane >> 4;
  const int hb = wv >> 1;          // unit-half this wave finalizes

  u32* hbuf = (u32*)(ws + OFF_H);
  const u16* wf = (const u16*)(ws + OFF_WF);

  __shared__ f32x4 red[2][4][4][64];   // [t&1][src_wave][ntile][lane], 32 KiB

  float bias[2];
  {
    int u7 = cl & 7;
    int R0 = (cl >> 3) * 512 + wg * 16 + hb * 8 + u7;        // i|f
    int R1 = (2 + (cl >> 3)) * 512 + wg * 16 + hb * 8 + u7;  // g|o
    bias[0] = bih[R0] + bhh[R0];
    bias[1] = bih[R1] + bhh[R1];
  }

  // resident B-fragments (normal loads; compiler may AGPR them):
  // BH[j][2*nt+{0,1}] = W_hh chunk (8+wv+4j), ntile nt, {hi,lo}
  // WB[J][2*nt+{0,1}] = W_ih chunk (4J+wv), ntile nt, {hi,lo}
  u32x4 BH[4][8], WB[2][8];
#pragma unroll
  for (int j = 0; j < 4; ++j)
#pragma unroll
    for (int nt = 0; nt < 4; ++nt) {
      const u32x4* p = (const u32x4*)(wf + ((((size_t)wg*4 + nt)*24 + (8 + wv + 4*j))*64 + lane)*16);
      BH[j][2*nt]   = p[0];
      BH[j][2*nt+1] = p[1];
    }
#pragma unroll
  for (int J = 0; J < 2; ++J)
#pragma unroll
    for (int nt = 0; nt < 4; ++nt) {
      const u32x4* p = (const u32x4*)(wf + ((((size_t)wg*4 + nt)*24 + (4*J + wv))*64 + lane)*16);
      WB[J][2*nt]   = p[0];
      WB[J][2*nt+1] = p[1];
    }

  const int brow = g * 16 + cl;                 // this lane's batch row
  const int koA = wv * 32 + 8 * gq;             // emb chunk wv
  const int koB = (4 + wv) * 32 + 8 * gq;       // emb chunk 4+wv

  // prologue: EA(t=0) via asm loads, fully drained
  u32x4 EA[4];
  {
    int tok0 = xin[brow * 512];
    const float* eb = emb + (size_t)tok0 * 256;
    LOADP(EA[0], eb + koA); LOADP(EA[1], eb + koA + 4);
    LOADP(EA[2], eb + koB); LOADP(EA[3], eb + koB + 4);
  }
  WAITV(0);

  float cst[4] = {0.f, 0.f, 0.f, 0.f};
  int delay = 16;                // adaptive sampling delay, s_sleep(1) units

  for (int t = 0; t < 512; ++t) {
    const u32* hc = hbuf + ((size_t)(t & 1) * 4 + g) * 8192;
    u32* hn = hbuf + ((size_t)((t + 1) & 1) * 4 + g) * 8192;
    const u32 texp = (u32)((t >> 1) & 1);
    const u32* pp[4];
    pp[0] = hc + cl * 512 + (wv + 0) * 32 + 8 * gq;
    pp[1] = hc + cl * 512 + (wv + 4) * 32 + 8 * gq;
    pp[2] = hc + cl * 512 + (wv + 8) * 32 + 8 * gq;
    pp[3] = hc + cl * 512 + (wv + 12) * 32 + 8 * gq;

    // ---- phase-1: emb projection, x_hi * (w_hi + w_lo)   [wait EA only] ----
    WAITV(4);
    f32x4 acc[4] = {};
    {
      u32x4 h0, h1;
      h0[0] = pkhi(EA[0][0], EA[0][1]); h0[1] = pkhi(EA[0][2], EA[0][3]);
      h0[2] = pkhi(EA[1][0], EA[1][1]); h0[3] = pkhi(EA[1][2], EA[1][3]);
      h1[0] = pkhi(EA[2][0], EA[2][1]); h1[1] = pkhi(EA[2][2], EA[2][3]);
      h1[2] = pkhi(EA[3][0], EA[3][1]); h1[3] = pkhi(EA[3][2], EA[3][3]);
      v8s a0 = BC(h0), a1 = BC(h1);
#pragma unroll
      for (int nt = 0; nt < 4; ++nt) {
        acc[nt] = MFMA16(a0, BC(WB[0][2*nt]),   acc[nt]);
        acc[nt] = MFMA16(a0, BC(WB[0][2*nt+1]), acc[nt]);
        acc[nt] = MFMA16(a1, BC(WB[1][2*nt]),   acc[nt]);
        acc[nt] = MFMA16(a1, BC(WB[1][2*nt+1]), acc[nt]);
      }
    }

    // ---- adaptive sampling delay: give producers their window ----
    for (int d = delay; d > 0; --d) __builtin_amdgcn_s_sleep(1);

    // ---- sample h: issue tok + 8 h loads (queue: [ST4, tok, H8]) ----
    int tok;
    asm volatile("global_load_dword %0, %1, off"
                 : "=v"(tok) : "v"(xin + brow * 512 + ((t + 1) & 511)));
    u32x4 HA[8];
    ISSUEJ(0); ISSUEJ(1); ISSUEJ(2); ISSUEJ(3);
    __builtin_amdgcn_sched_barrier(0);

    // ---- counted tagged consume: chunk j ready at vmcnt(6-2j) ----
    u32 pend = 0;
    WAITV(6); if (TAGOK(0)) { CONSJ(0); } else pend |= 1u;
    WAITV(4); if (TAGOK(1)) { CONSJ(1); } else pend |= 2u;
    WAITV(2); if (TAGOK(2)) { CONSJ(2); } else pend |= 4u;
    WAITV(0); if (TAGOK(3)) { CONSJ(3); } else pend |= 8u;

    // adaptive update: miss -> +8 (cap 64); hit -> -1 (floor 0)
    delay = pend ? ((delay > 56) ? 64 : delay + 8) : ((delay > 0) ? delay - 1 : 0);

    int fuse = 0;
    while (pend) {           // backoff re-poll; fuse = loud failure, no hang
      __builtin_amdgcn_s_sleep(1);
      RISS(0); RISS(1); RISS(2); RISS(3);
      WAITV(0);
      RCON(0); RCON(1); RCON(2); RCON(3);
      if (++fuse > 16384) break;
    }
    // vmcnt==0 here: tok resident; bind so no use is hoisted above
    asm volatile("s_waitcnt vmcnt(0)" : "+v"(tok) :: "memory");
    __builtin_amdgcn_sched_barrier(0);

    // ---- cross-wave K-reduction (double-buffered; barrier vmcnt(0) is free)
#pragma unroll
    for (int nt = 0; nt < 4; ++nt) red[t & 1][wv][nt][lane] = acc[nt];
    __syncthreads();

    // ---- EA reissue for t+1 (AFTER barrier: no drain stall) ----
    {
      const float* eb = emb + (size_t)(u32)tok * 256;
      LOADP(EA[0], eb + koA); LOADP(EA[1], eb + koA + 4);
      LOADP(EA[2], eb + koB); LOADP(EA[3], eb + koB + 4);
    }

    // wave-pair duplicate reduce: this wave finalizes unit-half hb
    const int n0 = hb * 2;
    f32x4 fin0 = red[t & 1][0][n0][lane] + red[t & 1][1][n0][lane]
               + red[t & 1][2][n0][lane] + red[t & 1][3][n0][lane];
    f32x4 fin1 = red[t & 1][0][n0+1][lane] + red[t & 1][1][n0+1][lane]
               + red[t & 1][2][n0+1][lane] + red[t & 1][3][n0+1][lane];
    fin0 += bias[0];
    fin1 += bias[1];

    // ---- gates: cols [i(0..7) f(8..15)] in fin0, [g(0..7) o(8..15)] in fin1
    const u32 tagn = (u32)(((t + 1) >> 1) & 1);
#pragma unroll
    for (int r = 0; r < 4; ++r) {
      float iv = fin0[r];
      float gv = fin1[r];
      float fv = __shfl_xor(iv, 8, 64);
      float ov = __shfl_xor(gv, 8, 64);
      float ii = sigm(iv);
      float ff = sigm(fv);
      float gg = tanhf_fast(gv);
      float oo = sigm(ov);
      float cn = ff * cst[r] + ii * gg;
      cst[r] = cn;
      float hnv = oo * tanhf_fast(cn);
      // wave pair splits stores by gq parity: 16 lanes x 4 r = 4 stores/wave
      if (((gq ^ wv) & 1) == 0 && cl < 8) {
        int row = 4 * gq + r;
        int jj = wg * 16 + hb * 8 + cl;
        if (t < 511) {
          u16 hi = bf_hi(hnv);
          u16 lo = bf_hi(hnv - bf_up(hi));
          u32 word = ((u32)hi << 16) | ((u32)lo & 0xfffeu) | tagn;
          STORED(hn + row * 512 + jj, word);
        } else {
          int b = g * 16 + row;
          dout[320 + b * 512 + jj] = hnv;            // h_t
          dout[320 + 32768 + b * 512 + jj] = cn;     // c_t
        }
      }
    }
  }
}

// ---------------- final projection: out = h_T @ W_out^T + b_out --------------
__global__ void k_out(const float* __restrict__ Wout, const float* __restrict__ bout,
                      float* __restrict__ dout) {
  int i = threadIdx.x;
  if (i >= 320) return;
  int b = i / 5, o = i - b * 5;
  const float* hp = dout + 320 + b * 512;
  const float* wp = Wout + (size_t)o * 512;
  float s = 0.f;
#pragma unroll 4
  for (int k = 0; k < 512; k += 4) {
    s += hp[k] * wp[k] + hp[k + 1] * wp[k + 1] + hp[k + 2] * wp[k + 2] + hp[k + 3] * wp[k + 3];
  }
  dout[i] = s + bout[o];
}

extern "C" void kernel_launch(void* const* d_in, const int* in_sizes, int n_in,
                              void* d_out, int out_size, void* d_ws, size_t ws_size,
                              hipStream_t stream) {
  const int* x = (const int*)d_in[0];
  const float* emb = (const float*)d_in[1];
  const float* Wih = (const float*)d_in[2];
  const float* bih = (const float*)d_in[3];
  const float* Whh = (const float*)d_in[4];
  const float* bhh = (const float*)d_in[5];
  const float* Wout = (const float*)d_in[6];
  const float* bout = (const float*)d_in[7];
  float* out = (float*)d_out;
  uint8_t* ws = (uint8_t*)d_ws;

  hipLaunchKernelGGL(k_init, dim3(256), dim3(256), 0, stream, (u32*)ws);
  hipLaunchKernelGGL(k_prep, dim3(768), dim3(256), 0, stream, Wih, Whh, (u16*)(ws + OFF_WF));
  hipLaunchKernelGGL(k_lstm, dim3(128), dim3(256), 0, stream, x, emb, bih, bhh, ws, out);
  hipLaunchKernelGGL(k_out, dim3(1), dim3(320), 0, stream, Wout, bout, out);
}

// Round 15
// 1668.841 us; speedup vs baseline: 1.0653x; 1.0653x over previous
//
#include <hip/hip_runtime.h>
#include <stdint.h>

typedef unsigned short u16;
typedef uint32_t u32;
typedef __attribute__((ext_vector_type(4))) u32 u32x4;
typedef __attribute__((ext_vector_type(8))) short v8s;
typedef __attribute__((ext_vector_type(4))) float f32x4;

// ---------------- workspace layout (bytes) ----------------
// h  : u32 [2 buf][4 grp][16 row][512 hid]   @ 0        (262144 B)
//      word = (bf16_hi<<16)|(bf16_lo&0xFFFE)|tag, tag=(t>>1)&1
// wf : u16 [64][2][24][64][16]               @ 262144   (6291456 B)
#define OFF_H  0
#define OFF_WF 262144

__device__ __forceinline__ u16 bf_hi(float v) {
  return (u16)(__builtin_bit_cast(u32, v) >> 16);
}
__device__ __forceinline__ float bf_up(u16 h) {
  return __builtin_bit_cast(float, (u32)h << 16);
}
__device__ __forceinline__ float tanhf_fast(float x) {
  float e = __expf(2.f * x);
  return 1.f - 2.f / (e + 1.f);
}
__device__ __forceinline__ float sigm(float x) {
  return 1.f / (1.f + __expf(-x));
}
// v_perm_b32 packers: pkhi(a,b) = (b&0xffff0000)|(a>>16); pklo = (b<<16)|(a&0xffff)
__device__ __forceinline__ u32 pkhi(u32 a, u32 b) { return __builtin_amdgcn_perm(b, a, 0x07060302u); }
__device__ __forceinline__ u32 pklo(u32 a, u32 b) { return __builtin_amdgcn_perm(b, a, 0x05040100u); }

// ---------------- init: buf0 = 0 (h0 valid, tag 0), buf1 = 1 (invalid at t=1)
__global__ void k_init(u32* h) {
  int i = blockIdx.x * 256 + threadIdx.x;   // 65536 words
  if (i < 65536) h[i] = (i < 32768) ? 0u : 1u;
}

// ---------------- pre-pack W_ih / W_hh into MFMA fragment order, bf16 hi/lo --
// chunk c: 0..7 -> W_ih (K'=c*32), 8..23 -> W_hh (K=(c-8)*32)
// B[k][n32] = W[R(n32)][k], R(n32) = (n32>>3)*512 + wg*8 + (n32&7)
__global__ void k_prep(const float* __restrict__ Wih, const float* __restrict__ Whh,
                       u16* __restrict__ wf) {
  int idx = blockIdx.x * 256 + threadIdx.x;
  if (idx >= 64 * 2 * 24 * 64) return;
  int lane = idx & 63;
  int r1 = idx >> 6;
  int c  = r1 % 24;
  int r2 = r1 / 24;
  int nt = r2 & 1;
  int wg = r2 >> 1;
  int n32 = nt * 16 + (lane & 15);
  int R = (n32 >> 3) * 512 + wg * 8 + (n32 & 7);
  int gq = lane >> 4;
  const float* src = (c < 8) ? (Wih + (size_t)R * 256 + c * 32 + 8 * gq)
                             : (Whh + (size_t)R * 512 + (c - 8) * 32 + 8 * gq);
  u16* d = wf + (size_t)idx * 16;
#pragma unroll
  for (int i = 0; i < 8; ++i) {
    float v = src[i];
    u16 hi = bf_hi(v);
    float lo = v - bf_up(hi);
    d[i] = hi;
    d[8 + i] = bf_hi(lo);
  }
}

// ---------------- asm helpers ----------------
#define LOADP(DST, PTR) \
  asm volatile("global_load_dwordx4 %0, %1, off" : "=v"(DST) : "v"(PTR))
#define LOADC(DST, PTR) \
  asm volatile("global_load_dwordx4 %0, %1, off sc0 sc1" : "=v"(DST) : "v"(PTR))
#define STORED(PTR, VAL) \
  asm volatile("global_store_dword %0, %1, off sc0 sc1" :: "v"(PTR), "v"(VAL) : "memory")

#define WAITV_(N) { asm volatile("s_waitcnt vmcnt(" #N ")" ::: "memory"); \
                    __builtin_amdgcn_sched_barrier(0); }
#define WAITV(N) WAITV_(N)

#define MFMA16(a, b, c) __builtin_amdgcn_mfma_f32_16x16x32_bf16((a), (b), (c), 0, 0, 0)
#define BC(x) __builtin_bit_cast(v8s, x)

// 6 MFMAs of one K-chunk: A (ah,al) x B {b0h,b0l,b1h,b1l} -> acc[0..1]
#define MM6(AH, AL, B) { \
  v8s b0h_ = BC((B)[0]), b0l_ = BC((B)[1]), b1h_ = BC((B)[2]), b1l_ = BC((B)[3]); \
  acc[0] = MFMA16((AH), b0h_, acc[0]); \
  acc[0] = MFMA16((AH), b0l_, acc[0]); \
  acc[0] = MFMA16((AL), b0h_, acc[0]); \
  acc[1] = MFMA16((AH), b1h_, acc[1]); \
  acc[1] = MFMA16((AH), b1l_, acc[1]); \
  acc[1] = MFMA16((AL), b1h_, acc[1]); }

// tag check of chunk j: all 8 LSBs == texp (wave-uniform verdict)
#define TAGOK(j) (__all((( (HA[2*(j)][0]^texp) | (HA[2*(j)][1]^texp) \
                         | (HA[2*(j)][2]^texp) | (HA[2*(j)][3]^texp) \
                         | (HA[2*(j)+1][0]^texp) | (HA[2*(j)+1][1]^texp) \
                         | (HA[2*(j)+1][2]^texp) | (HA[2*(j)+1][3]^texp)) & 1u) == 0u))

// consume chunk j: perm-unpack hi/lo + 6 MFMAs with BH[j]
#define CONSJ(j) { \
  u32x4 w0 = HA[2*(j)], w1 = HA[2*(j)+1]; \
  u32x4 hiw, low; \
  hiw[0] = pkhi(w0[0], w0[1]); hiw[1] = pkhi(w0[2], w0[3]); \
  hiw[2] = pkhi(w1[0], w1[1]); hiw[3] = pkhi(w1[2], w1[3]); \
  low[0] = pklo(w0[0], w0[1]); low[1] = pklo(w0[2], w0[3]); \
  low[2] = pklo(w1[0], w1[1]); low[3] = pklo(w1[2], w1[3]); \
  v8s ah = BC(hiw), al = BC(low); \
  MM6(ah, al, BH[j]); }

#define ISSUEJ(j) { LOADC(HA[2*(j)], pp[j]); LOADC(HA[2*(j)+1], pp[j] + 4); }
#define RISS(c)  if (pend & (1u<<(c))) ISSUEJ(c)
#define RCON(c)  if (pend & (1u<<(c))) { if (TAGOK(c)) { CONSJ(c); pend &= ~(1u<<(c)); } }

// ---------------- persistent recurrence kernel ----------------
// r15 = r11 (best validated, 1675us) + controller damping:
//   decay -1 only on even steps (equilibrium miss ~1/17 vs 1/9), init 24.
// Grid 256 = 4 batch-groups x 64 WGs, 256 thr (4 waves). Group g owns rows
// [g*16,g*16+16); WG wg owns hidden octet [wg*8,wg*8+8) x4 gates. Waves split
// K 4-ways; one barrier/step (red double-buffered). vmcnt ledger: loop-top
// queue [EA4, ST4]; phase-1 waits vmcnt(4); after +tok+H8 chunk j ready at
// vmcnt(7-2j)... (tok after H8 per r11 order: [ST4, tok, H8] -> 7/5/3/1),
// tok at vmcnt(0). EA reissue AFTER __syncthreads (barrier drain free).
__global__ __launch_bounds__(256, 1) void k_lstm(
    const int* __restrict__ xin, const float* __restrict__ emb,
    const float* __restrict__ bih, const float* __restrict__ bhh,
    uint8_t* __restrict__ ws, float* __restrict__ dout)
{
  const int bid = blockIdx.x;
  const int wg = bid & 63;
  const int g  = bid >> 6;
  const int tid = threadIdx.x;
  const int wv = tid >> 6;
  const int lane = tid & 63;
  const int cl = lane & 15;
  const int gq = lane >> 4;

  u32* hbuf = (u32*)(ws + OFF_H);
  const u16* wf = (const u16*)(ws + OFF_WF);

  __shared__ f32x4 red[2][4][2][64];   // [t&1][src_wave][ntile][lane], 16 KiB

  float bias[2];
#pragma unroll
  for (int nt = 0; nt < 2; ++nt) {
    int n32 = nt * 16 + cl;
    int R = (n32 >> 3) * 512 + wg * 8 + (n32 & 7);
    bias[nt] = bih[R] + bhh[R];
  }

  // resident B-fragments (normal loads; compiler may AGPR them):
  // W_hh chunks (8 + wv + 4j), W_ih chunks (4J + wv); each {b0h,b0l,b1h,b1l}
  u32x4 BH[4][4], WB[2][4];
#pragma unroll
  for (int j = 0; j < 4; ++j) {
    const u32x4* p0 = (const u32x4*)(wf + ((((size_t)wg*2+0)*24 + (8 + wv + 4*j))*64 + lane)*16);
    const u32x4* p1 = (const u32x4*)(wf + ((((size_t)wg*2+1)*24 + (8 + wv + 4*j))*64 + lane)*16);
    BH[j][0] = p0[0]; BH[j][1] = p0[1];
    BH[j][2] = p1[0]; BH[j][3] = p1[1];
  }
#pragma unroll
  for (int J = 0; J < 2; ++J) {
    const u32x4* p0 = (const u32x4*)(wf + ((((size_t)wg*2+0)*24 + (4*J + wv))*64 + lane)*16);
    const u32x4* p1 = (const u32x4*)(wf + ((((size_t)wg*2+1)*24 + (4*J + wv))*64 + lane)*16);
    WB[J][0] = p0[0]; WB[J][1] = p0[1];
    WB[J][2] = p1[0]; WB[J][3] = p1[1];
  }

  const int brow = g * 16 + cl;                 // this lane's batch row
  const int koA = wv * 32 + 8 * gq;             // emb chunk wv
  const int koB = (4 + wv) * 32 + 8 * gq;       // emb chunk 4+wv

  // prologue: EA(t=0) via asm loads, fully drained
  u32x4 EA[4];
  {
    int tok0 = xin[brow * 512];
    const float* eb = emb + (size_t)tok0 * 256;
    LOADP(EA[0], eb + koA); LOADP(EA[1], eb + koA + 4);
    LOADP(EA[2], eb + koB); LOADP(EA[3], eb + koB + 4);
  }
  WAITV(0);

  float cst[4] = {0.f, 0.f, 0.f, 0.f};
  int delay = 24;                // adaptive sampling delay, s_sleep(1) units

  for (int t = 0; t < 512; ++t) {
    const u32* hc = hbuf + ((size_t)(t & 1) * 4 + g) * 8192;
    u32* hn = hbuf + ((size_t)((t + 1) & 1) * 4 + g) * 8192;
    const u32 texp = (u32)((t >> 1) & 1);
    const u32* pp[4];
    pp[0] = hc + cl * 512 + (wv + 0) * 32 + 8 * gq;
    pp[1] = hc + cl * 512 + (wv + 4) * 32 + 8 * gq;
    pp[2] = hc + cl * 512 + (wv + 8) * 32 + 8 * gq;
    pp[3] = hc + cl * 512 + (wv + 12) * 32 + 8 * gq;

    // ---- phase-1: emb projection, x_hi * (w_hi + w_lo)   [wait EA only] ----
    WAITV(4);
    f32x4 acc[2] = {};
    {
      u32x4 h0, h1;
      h0[0] = pkhi(EA[0][0], EA[0][1]); h0[1] = pkhi(EA[0][2], EA[0][3]);
      h0[2] = pkhi(EA[1][0], EA[1][1]); h0[3] = pkhi(EA[1][2], EA[1][3]);
      h1[0] = pkhi(EA[2][0], EA[2][1]); h1[1] = pkhi(EA[2][2], EA[2][3]);
      h1[2] = pkhi(EA[3][0], EA[3][1]); h1[3] = pkhi(EA[3][2], EA[3][3]);
      v8s a0 = BC(h0), a1 = BC(h1);
      acc[0] = MFMA16(a0, BC(WB[0][0]), acc[0]);
      acc[0] = MFMA16(a0, BC(WB[0][1]), acc[0]);
      acc[1] = MFMA16(a0, BC(WB[0][2]), acc[1]);
      acc[1] = MFMA16(a0, BC(WB[0][3]), acc[1]);
      acc[0] = MFMA16(a1, BC(WB[1][0]), acc[0]);
      acc[0] = MFMA16(a1, BC(WB[1][1]), acc[0]);
      acc[1] = MFMA16(a1, BC(WB[1][2]), acc[1]);
      acc[1] = MFMA16(a1, BC(WB[1][3]), acc[1]);
    }

    // ---- adaptive sampling delay: give producers their window ----
    for (int d = delay; d > 0; --d) __builtin_amdgcn_s_sleep(1);

    // ---- sample h: issue tok + 8 h loads (queue: [ST4, tok, H8]) ----
    int tok;
    asm volatile("global_load_dword %0, %1, off"
                 : "=v"(tok) : "v"(xin + brow * 512 + ((t + 1) & 511)));
    u32x4 HA[8];
    ISSUEJ(0); ISSUEJ(1); ISSUEJ(2); ISSUEJ(3);
    __builtin_amdgcn_sched_barrier(0);

    // ---- counted tagged consume: chunk j ready at vmcnt(6-2j) ----
    u32 pend = 0;
    WAITV(6); if (TAGOK(0)) { CONSJ(0); } else pend |= 1u;
    WAITV(4); if (TAGOK(1)) { CONSJ(1); } else pend |= 2u;
    WAITV(2); if (TAGOK(2)) { CONSJ(2); } else pend |= 4u;
    WAITV(0); if (TAGOK(3)) { CONSJ(3); } else pend |= 8u;

    // damped adaptive update: miss -> +8 (cap 64); hit -> -1 on even steps only
    delay = pend ? ((delay > 56) ? 64 : delay + 8)
                 : ((delay > 0 && (t & 1) == 0) ? delay - 1 : delay);

    int fuse = 0;
    while (pend) {           // backoff re-poll; fuse = loud failure, no hang
      __builtin_amdgcn_s_sleep(1);
      RISS(0); RISS(1); RISS(2); RISS(3);
      WAITV(0);
      RCON(0); RCON(1); RCON(2); RCON(3);
      if (++fuse > 16384) break;
    }
    // vmcnt==0 here: tok resident; bind so no use is hoisted above
    asm volatile("s_waitcnt vmcnt(0)" : "+v"(tok) :: "memory");
    __builtin_amdgcn_sched_barrier(0);

    // ---- cross-wave K-reduction (double-buffered; barrier vmcnt(0) is free)
    red[t & 1][wv][0][lane] = acc[0];
    red[t & 1][wv][1][lane] = acc[1];
    __syncthreads();

    // ---- EA reissue for t+1 (AFTER barrier: no drain stall) ----
    {
      const float* eb = emb + (size_t)(u32)tok * 256;
      LOADP(EA[0], eb + koA); LOADP(EA[1], eb + koA + 4);
      LOADP(EA[2], eb + koB); LOADP(EA[3], eb + koB + 4);
    }

    f32x4 fin0 = red[t & 1][0][0][lane] + red[t & 1][1][0][lane]
               + red[t & 1][2][0][lane] + red[t & 1][3][0][lane];
    f32x4 fin1 = red[t & 1][0][1][lane] + red[t & 1][1][1][lane]
               + red[t & 1][2][1][lane] + red[t & 1][3][1][lane];
    fin0 += bias[0];
    fin1 += bias[1];

    // ---- gates: cols [i(0..7) f(8..15)] in fin0, [g(0..7) o(8..15)] in fin1
    const u32 tagn = (u32)(((t + 1) >> 1) & 1);
#pragma unroll
    for (int r = 0; r < 4; ++r) {
      float iv = fin0[r];
      float gv = fin1[r];
      float fv = __shfl_xor(iv, 8, 64);
      float ov = __shfl_xor(gv, 8, 64);
      float ii = sigm(iv);
      float ff = sigm(fv);
      float gg = tanhf_fast(gv);
      float oo = sigm(ov);
      float cn = ff * cst[r] + ii * gg;
      cst[r] = cn;
      float hnv = oo * tanhf_fast(cn);
      // wave wv stores rows 4*wv+r (gq==wv lanes): 4-way parallel store issue
      if (gq == wv && cl < 8) {
        int row = 4 * gq + r;
        int jj = wg * 8 + cl;
        if (t < 511) {
          u16 hi = bf_hi(hnv);
          u16 lo = bf_hi(hnv - bf_up(hi));
          u32 word = ((u32)hi << 16) | ((u32)lo & 0xfffeu) | tagn;
          STORED(hn + row * 512 + jj, word);
        } else {
          int b = g * 16 + row;
          dout[320 + b * 512 + jj] = hnv;            // h_t
          dout[320 + 32768 + b * 512 + jj] = cn;     // c_t
        }
      }
    }
  }
}

// ---------------- final projection: out = h_T @ W_out^T + b_out --------------
__global__ void k_out(const float* __restrict__ Wout, const float* __restrict__ bout,
                      float* __restrict__ dout) {
  int i = threadIdx.x;
  if (i >= 320) return;
  int b = i / 5, o = i - b * 5;
  const float* hp = dout + 320 + b * 512;
  const float* wp = Wout + (size_t)o * 512;
  float s = 0.f;
#pragma unroll 4
  for (int k = 0; k < 512; k += 4) {
    s += hp[k] * wp[k] + hp[k + 1] * wp[k + 1] + hp[k + 2] * wp[k + 2] + hp[k + 3] * wp[k + 3];
  }
  dout[i] = s + bout[o];
}

extern "C" void kernel_launch(void* const* d_in, const int* in_sizes, int n_in,
                              void* d_out, int out_size, void* d_ws, size_t ws_size,
                              hipStream_t stream) {
  const int* x = (const int*)d_in[0];
  const float* emb = (const float*)d_in[1];
  const float* Wih = (const float*)d_in[2];
  const float* bih = (const float*)d_in[3];
  const float* Whh = (const float*)d_in[4];
  const float* bhh = (const float*)d_in[5];
  const float* Wout = (const float*)d_in[6];
  const float* bout = (const float*)d_in[7];
  float* out = (float*)d_out;
  uint8_t* ws = (uint8_t*)d_ws;

  hipLaunchKernelGGL(k_init, dim3(256), dim3(256), 0, stream, (u32*)ws);
  hipLaunchKernelGGL(k_prep, dim3(768), dim3(256), 0, stream, Wih, Whh, (u16*)(ws + OFF_WF));
  hipLaunchKernelGGL(k_lstm, dim3(256), dim3(256), 0, stream, x, emb, bih, bhh, ws, out);
  hipLaunchKernelGGL(k_out, dim3(1), dim3(320), 0, stream, Wout, bout, out);
}